// Round 4
// baseline (24.234 us; speedup 1.0000x reference)
//
#include <hip/hip_runtime.h>

// Problem constants (fixed by the reference)
#define BB   4096
#define NN   16
#define AA   8
#define DIN  128
#define H1C  64
#define DPC  64
#define DZC  64

#define GENV 8     // envs per block
#define WENV 2     // envs per wave (ILP factor)
#define NTHR 256   // 4 waves per block

// Collapsed reference (round-0 derivation, verified passing rounds 1/3):
//   agg   = mean_n obs[b,n,:]                      [128]
//   h     = relu(agg @ W1 + b1)                    [64]
//   p     = h @ W2 + b2        (only used via two dots -> eliminated:)
//     u  = Wfc @ (Wattn[:64]+Wattn[64:])   [64]  (env-independent)
//     v1 = W2 @ u, v2 = W2 @ Wv[:64]      [64]  (env-independent)
//   logit = h.v1 + b2.u ;  wgt = sigmoid(leaky_relu(logit))
//   c     = h.v2 + b2.Wv[:64] + bv
//   dv[j] = (pi[b,j]-act[b,j]) . Wv[64:72]        [16]
//   Sv    = sum(pi.v) - wgt * sum((pi-act).v)
//   x[b,d,j] = c + (Sv + wgt*dv[j]) / 16          (independent of d)
__global__ __launch_bounds__(NTHR, 2)
void critic_kernel(const float* __restrict__ obs,      // [B*N, 128]
                   const float* __restrict__ policies, // [B*N, 8]
                   const float* __restrict__ actions,  // [B*N, 8]
                   const float* __restrict__ W1,       // [128,64]
                   const float* __restrict__ b1,       // [64]
                   const float* __restrict__ W2,       // [64,64]
                   const float* __restrict__ b2,       // [64]
                   const float* __restrict__ Wfc,      // [64,64]
                   const float* __restrict__ Wattn,    // [128]
                   const float* __restrict__ Wv,       // [72]
                   const float* __restrict__ bv,       // [1]
                   float* __restrict__ out_x,          // [B*N*N]
                   float* __restrict__ out_w)          // [B*N*N]
{
    __shared__ float sW1[DIN * H1C];    // 32 KB
    __shared__ float sAgg[GENV][DIN];   // 4 KB
    __shared__ float sWsum[DZC];        // 256 B
    __shared__ float sWv64[DPC];        // 256 B
    __shared__ float sU[DPC];           // 256 B
    __shared__ float sDv[GENV][16];     // 512 B

    const int tid = threadIdx.x;
    const int l   = tid & 63;
    const int wv  = tid >> 6;
    const int le0 = wv * WENV;                       // local env base of this wave
    const int e0  = blockIdx.x * GENV + le0;         // global env base of this wave

    // ---- hoisted small params ----
    const float b1v = b1[l];
    const float b2v = b2[l];
    const float wa0 = Wattn[l];
    const float wa1 = Wattn[DZC + l];
    const float wvv = Wv[l];
    const float va  = Wv[64 + (l & 7)];
    const float bvv = bv[0];

    // ---- stage W1 into LDS (cooperative, 8 float4 per thread) ----
    {
        const float4* g1 = reinterpret_cast<const float4*>(W1);
        float4*       s1 = reinterpret_cast<float4*>(sW1);
        #pragma unroll
        for (int i = 0; i < (DIN * H1C / 4) / NTHR; ++i)
            s1[i * NTHR + tid] = g1[i * NTHR + tid];
    }

    // ---- obs means per env (round-1/3 order: per-lane sum of 8, xor-32) ----
    #pragma unroll
    for (int ee = 0; ee < WENV; ++ee) {
        const float4* o4 = reinterpret_cast<const float4*>(obs + (size_t)(e0 + ee) * NN * DIN);
        float4 a = make_float4(0.f, 0.f, 0.f, 0.f);
        #pragma unroll
        for (int t = 0; t < 8; ++t) {
            const float4 v = o4[t * 64 + l];
            a.x += v.x; a.y += v.y; a.z += v.z; a.w += v.w;
        }
        a.x += __shfl_xor(a.x, 32);
        a.y += __shfl_xor(a.y, 32);
        a.z += __shfl_xor(a.z, 32);
        a.w += __shfl_xor(a.w, 32);
        if (l < 32) {
            const float inv = 1.0f / 16.0f;
            reinterpret_cast<float4*>(sAgg[le0 + ee])[l] =
                make_float4(a.x * inv, a.y * inv, a.z * inv, a.w * inv);
        }
    }

    // ---- policies/actions loads (early issue; used in phase F) ----
    float pv0[WENV], pv1[WENV], av0[WENV], av1[WENV];
    #pragma unroll
    for (int ee = 0; ee < WENV; ++ee) {
        const float* Pb = policies + (size_t)(e0 + ee) * (NN * AA);
        const float* Ab = actions  + (size_t)(e0 + ee) * (NN * AA);
        pv0[ee] = Pb[l]; pv1[ee] = Pb[64 + l];
        av0[ee] = Ab[l]; av1[ee] = Ab[64 + l];
    }

    // ---- small shared vectors (wave 0 writes; all waves read after barrier) ----
    if (tid < 64) {
        sWsum[l] = wa0 + wa1;
        sWv64[l] = wvv;
    }

    __syncthreads();   // sW1, sAgg, sWsum, sWv64 visible

    // ---- u = Wfc @ wsum : lane l = row l (all waves redundantly, bit-identical) ----
    float u = 0.0f;
    {
        const float4* WfcR = reinterpret_cast<const float4*>(Wfc + (size_t)l * DZC);
        const float4* ws4  = reinterpret_cast<const float4*>(sWsum);
        #pragma unroll
        for (int j4 = 0; j4 < DZC / 4; ++j4) {
            const float4 w = WfcR[j4];
            const float4 s = ws4[j4];           // LDS broadcast
            u = fmaf(w.x, s.x, u); u = fmaf(w.y, s.y, u);
            u = fmaf(w.z, s.z, u); u = fmaf(w.w, s.w, u);
        }
    }
    sU[l] = u;   // all waves write identical values (benign)

    __syncthreads();   // sU visible

    // ---- v1 = W2 @ u, v2 = W2 @ Wv64 : lane l = row l ----
    float v1 = 0.0f, v2 = 0.0f;
    {
        const float4* W2R = reinterpret_cast<const float4*>(W2 + (size_t)l * DPC);
        const float4* su4 = reinterpret_cast<const float4*>(sU);
        const float4* sv4 = reinterpret_cast<const float4*>(sWv64);
        #pragma unroll
        for (int j4 = 0; j4 < DPC / 4; ++j4) {
            const float4 w = W2R[j4];
            const float4 a = su4[j4];
            const float4 b = sv4[j4];
            v1 = fmaf(w.x, a.x, v1); v1 = fmaf(w.y, a.y, v1);
            v1 = fmaf(w.z, a.z, v1); v1 = fmaf(w.w, a.w, v1);
            v2 = fmaf(w.x, b.x, v2); v2 = fmaf(w.y, b.y, v2);
            v2 = fmaf(w.z, b.z, v2); v2 = fmaf(w.w, b.w, v2);
        }
    }
    // scalars b2.u and b2.Wv64 (full-wave butterfly)
    float tb2u = b2v * u;
    float tb2w = b2v * wvv;
    #pragma unroll
    for (int m = 32; m >= 1; m >>= 1) {
        tb2u += __shfl_xor(tb2u, m);
        tb2w += __shfl_xor(tb2w, m);
    }

    // ---- mv1: h = relu(agg @ W1 + b1), lane = output col, 2-env ILP ----
    float acc0 = b1v, acc1 = b1v;
    #pragma unroll 8
    for (int d4 = 0; d4 < DIN / 4; ++d4) {
        const float w0  = sW1[(4 * d4 + 0) * H1C + l];
        const float w1_ = sW1[(4 * d4 + 1) * H1C + l];
        const float w2_ = sW1[(4 * d4 + 2) * H1C + l];
        const float w3_ = sW1[(4 * d4 + 3) * H1C + l];
        const float4 a0 = *reinterpret_cast<const float4*>(&sAgg[le0 + 0][4 * d4]);
        const float4 a1 = *reinterpret_cast<const float4*>(&sAgg[le0 + 1][4 * d4]);
        acc0 = fmaf(a0.x, w0, acc0); acc0 = fmaf(a0.y, w1_, acc0);
        acc0 = fmaf(a0.z, w2_, acc0); acc0 = fmaf(a0.w, w3_, acc0);
        acc1 = fmaf(a1.x, w0, acc1); acc1 = fmaf(a1.y, w1_, acc1);
        acc1 = fmaf(a1.z, w2_, acc1); acc1 = fmaf(a1.w, w3_, acc1);
    }
    const float hh[WENV] = { fmaxf(acc0, 0.0f), fmaxf(acc1, 0.0f) };

    // ---- per-env scalars (round-3 trees for pol/act, new h-dots for wgt/c) ----
    float wgt[WENV], cc[WENV], Svv[WENV];
    #pragma unroll
    for (int ee = 0; ee < WENV; ++ee) {
        const int le = le0 + ee;
        float t0 = hh[ee] * v1;
        float t1 = hh[ee] * v2;
        #pragma unroll
        for (int m = 32; m >= 1; m >>= 1) {
            t0 += __shfl_xor(t0, m);
            t1 += __shfl_xor(t1, m);
        }
        const float logit = t0 + tb2u;
        const float eV = (logit > 0.0f) ? logit : 0.01f * logit;  // leaky slope 0.01
        wgt[ee] = 1.0f / (1.0f + expf(-eV));
        cc[ee]  = t1 + tb2w + bvv;

        float q0 = (pv0[ee] - av0[ee]) * va;   // -> dv[l>>3]
        float q1 = (pv1[ee] - av1[ee]) * va;   // -> dv[8+(l>>3)]
        float fq = q0 + q1;
        float fp = (pv0[ee] + pv1[ee]) * va;
        #pragma unroll
        for (int m = 1; m <= 4; m <<= 1) {     // segmented 8-lane reduce (over a)
            q0 += __shfl_xor(q0, m);
            q1 += __shfl_xor(q1, m);
        }
        #pragma unroll
        for (int m = 32; m >= 1; m >>= 1) {    // full-wave reduces (round-3 tree)
            fq += __shfl_xor(fq, m);
            fp += __shfl_xor(fp, m);
        }
        Svv[ee] = fp - wgt[ee] * fq;

        if ((l & 7) == 0) {
            sDv[le][l >> 3]       = q0;
            sDv[le][8 + (l >> 3)] = q1;
        }
    }

    __syncthreads();   // sDv visible

    // ---- outputs: 16 distinct x per env, broadcast over d; w scalar ----
    const float invN = 1.0f / 16.0f;
    const int j0 = (4 * l) & 15;          // 0,4,8,12; j0..j0+3 never wrap
    #pragma unroll
    for (int ee = 0; ee < WENV; ++ee) {
        const int le = le0 + ee;
        float4 xo, wo;
        xo.x = fmaf(wgt[ee], sDv[le][j0 + 0], Svv[ee]) * invN + cc[ee];
        xo.y = fmaf(wgt[ee], sDv[le][j0 + 1], Svv[ee]) * invN + cc[ee];
        xo.z = fmaf(wgt[ee], sDv[le][j0 + 2], Svv[ee]) * invN + cc[ee];
        xo.w = fmaf(wgt[ee], sDv[le][j0 + 3], Svv[ee]) * invN + cc[ee];
        wo.x = wo.y = wo.z = wo.w = wgt[ee];

        const size_t base = (size_t)(e0 + ee) * (NN * NN) + 4 * l;
        *reinterpret_cast<float4*>(out_x + base) = xo;
        *reinterpret_cast<float4*>(out_w + base) = wo;
    }
}

extern "C" void kernel_launch(void* const* d_in, const int* in_sizes, int n_in,
                              void* d_out, int out_size, void* d_ws, size_t ws_size,
                              hipStream_t stream) {
    const float* obs      = (const float*)d_in[0];
    const float* policies = (const float*)d_in[1];
    const float* actions  = (const float*)d_in[2];
    const float* W1       = (const float*)d_in[3];
    const float* b1       = (const float*)d_in[4];
    const float* W2       = (const float*)d_in[5];
    const float* b2       = (const float*)d_in[6];
    const float* Wfc      = (const float*)d_in[7];
    const float* Wattn    = (const float*)d_in[8];
    const float* Wv       = (const float*)d_in[9];
    const float* bv       = (const float*)d_in[10];

    float* out_x = (float*)d_out;                    // [B*N*N] = 1048576
    float* out_w = out_x + (size_t)BB * NN * NN;     // second tuple element

    critic_kernel<<<BB / GENV, NTHR, 0, stream>>>(obs, policies, actions,
                                                  W1, b1, W2, b2, Wfc, Wattn, Wv, bv,
                                                  out_x, out_w);
}

// Round 5
// 21.972 us; speedup vs baseline: 1.1030x; 1.1030x over previous
//
#include <hip/hip_runtime.h>

// Problem constants (fixed by the reference)
#define BB   4096
#define NN   16
#define AA   8
#define DIN  128
#define H1C  64
#define DPC  64
#define DZC  64

#define GENV 8     // envs per block
#define WENV 4     // envs per wave (ILP factor)
#define NTHR 128   // 2 waves per block

// Collapsed reference (round-0 derivation; trees verified passing R1/R3/R4):
//   agg   = mean_n obs[b,n,:]                      [128]
//   h     = relu(agg @ W1 + b1)                    [64]
//   (p eliminated:)  u = Wfc @ (Wattn[:64]+Wattn[64:]);  v1 = W2 @ u;  v2 = W2 @ Wv[:64]
//   logit = h.v1 + b2.u ;  wgt = sigmoid(leaky_relu(logit))   -> entire w output
//   c     = h.v2 + b2.Wv[:64] + bv
//   dv[j] = (pi[b,j]-act[b,j]) . Wv[64:72]         [16]
//   Sv    = sum(pi.v) - wgt * sum((pi-act).v)
//   x[b,d,j] = c + (Sv + wgt*dv[j]) / 16           (independent of d)
__global__ __launch_bounds__(NTHR, 1)
void critic_kernel(const float* __restrict__ obs,      // [B*N, 128]
                   const float* __restrict__ policies, // [B*N, 8]
                   const float* __restrict__ actions,  // [B*N, 8]
                   const float* __restrict__ W1,       // [128,64]
                   const float* __restrict__ b1,       // [64]
                   const float* __restrict__ W2,       // [64,64]
                   const float* __restrict__ b2,       // [64]
                   const float* __restrict__ Wfc,      // [64,64]
                   const float* __restrict__ Wattn,    // [128]
                   const float* __restrict__ Wv,       // [72]
                   const float* __restrict__ bv,       // [1]
                   float* __restrict__ out_x,          // [B*N*N]
                   float* __restrict__ out_w)          // [B*N*N]
{
    __shared__ float sW1[DIN * H1C];    // 32 KB
    __shared__ float sAgg[GENV][DIN];   // 4 KB
    __shared__ float sDv[GENV][16];     // 0.5 KB   -> ~36.5 KB total, up to 4 blocks/CU

    const int tid = threadIdx.x;
    const int l   = tid & 63;
    const int wv  = tid >> 6;
    const int le0 = wv * WENV;                       // local env base of this wave
    const int e0  = blockIdx.x * GENV + le0;         // global env base of this wave

    // ---- hoisted small params ----
    const float b1v = b1[l];
    const float b2v = b2[l];
    const float wa0 = Wattn[l];
    const float wa1 = Wattn[DZC + l];
    const float wvv = Wv[l];
    const float va  = Wv[64 + (l & 7)];
    const float bvv = bv[0];

    // ---- obs loads, 2-env-deep pipeline: issue envs 0,1 now ----
    const size_t ob = (size_t)e0 * NN * DIN;
    const float4* o0 = reinterpret_cast<const float4*>(obs + ob);
    const float4* o1 = reinterpret_cast<const float4*>(obs + ob + 1 * NN * DIN);
    const float4* o2 = reinterpret_cast<const float4*>(obs + ob + 2 * NN * DIN);
    const float4* o3 = reinterpret_cast<const float4*>(obs + ob + 3 * NN * DIN);
    float4 ovA[8], ovB[8];
    #pragma unroll
    for (int t = 0; t < 8; ++t) ovA[t] = o0[t * 64 + l];
    #pragma unroll
    for (int t = 0; t < 8; ++t) ovB[t] = o1[t * 64 + l];

    // ---- stage W1 into LDS (cooperative, 16 float4 per thread) ----
    {
        const float4* g1 = reinterpret_cast<const float4*>(W1);
        float4*       s1 = reinterpret_cast<float4*>(sW1);
        #pragma unroll
        for (int i = 0; i < (DIN * H1C / 4) / NTHR; ++i)
            s1[i * NTHR + tid] = g1[i * NTHR + tid];
    }

    // ---- policies/actions loads (early issue) ----
    float pv0[WENV], pv1[WENV], av0[WENV], av1[WENV];
    #pragma unroll
    for (int ee = 0; ee < WENV; ++ee) {
        const float* Pb = policies + (size_t)(e0 + ee) * (NN * AA);
        const float* Ab = actions  + (size_t)(e0 + ee) * (NN * AA);
        pv0[ee] = Pb[l]; pv1[ee] = Pb[64 + l];
        av0[ee] = Ab[l]; av1[ee] = Ab[64 + l];
    }

    // ---- env-independent u/v1/v2: per-wave, registers + shuffles, no barriers.
    //      Same accumulation order as R4 (passed). Overlaps the obs drain. ----
    const float wsum = wa0 + wa1;
    float u = 0.0f;
    {
        const float4* WfcR = reinterpret_cast<const float4*>(Wfc) + (size_t)l * (DZC / 4);
        float4 wbuf[16];
        #pragma unroll
        for (int j4 = 0; j4 < 16; ++j4) wbuf[j4] = WfcR[j4];
        #pragma unroll
        for (int j4 = 0; j4 < 16; ++j4) {
            const float4 w = wbuf[j4];
            u = fmaf(w.x, __shfl(wsum, 4 * j4 + 0), u);
            u = fmaf(w.y, __shfl(wsum, 4 * j4 + 1), u);
            u = fmaf(w.z, __shfl(wsum, 4 * j4 + 2), u);
            u = fmaf(w.w, __shfl(wsum, 4 * j4 + 3), u);
        }
    }
    float v1 = 0.0f, v2 = 0.0f;
    {
        const float4* W2R = reinterpret_cast<const float4*>(W2) + (size_t)l * (DPC / 4);
        float4 wbuf[16];
        #pragma unroll
        for (int j4 = 0; j4 < 16; ++j4) wbuf[j4] = W2R[j4];
        #pragma unroll
        for (int j4 = 0; j4 < 16; ++j4) {
            const float4 w = wbuf[j4];
            v1 = fmaf(w.x, __shfl(u, 4 * j4 + 0), v1);
            v1 = fmaf(w.y, __shfl(u, 4 * j4 + 1), v1);
            v1 = fmaf(w.z, __shfl(u, 4 * j4 + 2), v1);
            v1 = fmaf(w.w, __shfl(u, 4 * j4 + 3), v1);
            v2 = fmaf(w.x, __shfl(wvv, 4 * j4 + 0), v2);
            v2 = fmaf(w.y, __shfl(wvv, 4 * j4 + 1), v2);
            v2 = fmaf(w.z, __shfl(wvv, 4 * j4 + 2), v2);
            v2 = fmaf(w.w, __shfl(wvv, 4 * j4 + 3), v2);
        }
    }
    // scalars b2.u and b2.Wv64 (R4 butterfly)
    float tb2u = b2v * u;
    float tb2w = b2v * wvv;
    #pragma unroll
    for (int m = 32; m >= 1; m >>= 1) {
        tb2u += __shfl_xor(tb2u, m);
        tb2w += __shfl_xor(tb2w, m);
    }

    // ---- obs means (R1/R3 tree: zero-init + 8 adds, xor-32, /16, lanes<32 store) ----
    auto sumstore = [&](const float4* v8, int le) {
        float4 a = make_float4(0.f, 0.f, 0.f, 0.f);
        #pragma unroll
        for (int t = 0; t < 8; ++t) {
            a.x += v8[t].x; a.y += v8[t].y; a.z += v8[t].z; a.w += v8[t].w;
        }
        a.x += __shfl_xor(a.x, 32);
        a.y += __shfl_xor(a.y, 32);
        a.z += __shfl_xor(a.z, 32);
        a.w += __shfl_xor(a.w, 32);
        if (l < 32) {
            const float inv = 1.0f / 16.0f;
            reinterpret_cast<float4*>(sAgg[le])[l] =
                make_float4(a.x * inv, a.y * inv, a.z * inv, a.w * inv);
        }
    };

    sumstore(ovA, le0 + 0);
    #pragma unroll
    for (int t = 0; t < 8; ++t) ovA[t] = o2[t * 64 + l];   // refill pipeline
    sumstore(ovB, le0 + 1);
    #pragma unroll
    for (int t = 0; t < 8; ++t) ovB[t] = o3[t * 64 + l];
    sumstore(ovA, le0 + 2);
    sumstore(ovB, le0 + 3);

    __syncthreads();   // sW1 (cross-wave) + sAgg visible

    // ---- mv1: h = relu(agg @ W1 + b1), lane = output col, 4-env ILP (R3 tree) ----
    float acc0 = b1v, acc1 = b1v, acc2 = b1v, acc3 = b1v;
    #pragma unroll 8
    for (int d4 = 0; d4 < DIN / 4; ++d4) {
        const float w0  = sW1[(4 * d4 + 0) * H1C + l];
        const float w1_ = sW1[(4 * d4 + 1) * H1C + l];
        const float w2_ = sW1[(4 * d4 + 2) * H1C + l];
        const float w3_ = sW1[(4 * d4 + 3) * H1C + l];
        const float4 a0 = *reinterpret_cast<const float4*>(&sAgg[le0 + 0][4 * d4]);
        const float4 a1 = *reinterpret_cast<const float4*>(&sAgg[le0 + 1][4 * d4]);
        const float4 a2 = *reinterpret_cast<const float4*>(&sAgg[le0 + 2][4 * d4]);
        const float4 a3 = *reinterpret_cast<const float4*>(&sAgg[le0 + 3][4 * d4]);
        acc0 = fmaf(a0.x, w0, acc0); acc0 = fmaf(a0.y, w1_, acc0);
        acc0 = fmaf(a0.z, w2_, acc0); acc0 = fmaf(a0.w, w3_, acc0);
        acc1 = fmaf(a1.x, w0, acc1); acc1 = fmaf(a1.y, w1_, acc1);
        acc1 = fmaf(a1.z, w2_, acc1); acc1 = fmaf(a1.w, w3_, acc1);
        acc2 = fmaf(a2.x, w0, acc2); acc2 = fmaf(a2.y, w1_, acc2);
        acc2 = fmaf(a2.z, w2_, acc2); acc2 = fmaf(a2.w, w3_, acc2);
        acc3 = fmaf(a3.x, w0, acc3); acc3 = fmaf(a3.y, w1_, acc3);
        acc3 = fmaf(a3.z, w2_, acc3); acc3 = fmaf(a3.w, w3_, acc3);
    }
    const float hh[WENV] = { fmaxf(acc0, 0.0f), fmaxf(acc1, 0.0f),
                             fmaxf(acc2, 0.0f), fmaxf(acc3, 0.0f) };

    // ---- per-env scalars (R4 h-dot trees; R3 pol/act trees) ----
    float wgt[WENV], cc[WENV], Svv[WENV];
    #pragma unroll
    for (int ee = 0; ee < WENV; ++ee) {
        const int le = le0 + ee;
        float t0 = hh[ee] * v1;
        float t1 = hh[ee] * v2;
        #pragma unroll
        for (int m = 32; m >= 1; m >>= 1) {
            t0 += __shfl_xor(t0, m);
            t1 += __shfl_xor(t1, m);
        }
        const float logit = t0 + tb2u;
        const float eV = (logit > 0.0f) ? logit : 0.01f * logit;  // leaky slope 0.01
        wgt[ee] = 1.0f / (1.0f + expf(-eV));
        cc[ee]  = t1 + tb2w + bvv;

        float q0 = (pv0[ee] - av0[ee]) * va;   // -> dv[l>>3]
        float q1 = (pv1[ee] - av1[ee]) * va;   // -> dv[8+(l>>3)]
        float fq = q0 + q1;
        float fp = (pv0[ee] + pv1[ee]) * va;
        #pragma unroll
        for (int m = 1; m <= 4; m <<= 1) {     // segmented 8-lane reduce (over a)
            q0 += __shfl_xor(q0, m);
            q1 += __shfl_xor(q1, m);
        }
        #pragma unroll
        for (int m = 32; m >= 1; m >>= 1) {    // full-wave reduces (R3 tree)
            fq += __shfl_xor(fq, m);
            fp += __shfl_xor(fp, m);
        }
        Svv[ee] = fp - wgt[ee] * fq;

        if ((l & 7) == 0) {
            sDv[le][l >> 3]       = q0;
            sDv[le][8 + (l >> 3)] = q1;
        }
    }

    __syncthreads();   // sDv visible

    // ---- outputs: 16 distinct x per env, broadcast over d; w scalar ----
    const float invN = 1.0f / 16.0f;
    const int j0 = (4 * l) & 15;          // 0,4,8,12; j0..j0+3 never wrap
    #pragma unroll
    for (int ee = 0; ee < WENV; ++ee) {
        const int le = le0 + ee;
        float4 xo, wo;
        xo.x = fmaf(wgt[ee], sDv[le][j0 + 0], Svv[ee]) * invN + cc[ee];
        xo.y = fmaf(wgt[ee], sDv[le][j0 + 1], Svv[ee]) * invN + cc[ee];
        xo.z = fmaf(wgt[ee], sDv[le][j0 + 2], Svv[ee]) * invN + cc[ee];
        xo.w = fmaf(wgt[ee], sDv[le][j0 + 3], Svv[ee]) * invN + cc[ee];
        wo.x = wo.y = wo.z = wo.w = wgt[ee];

        const size_t base = (size_t)(e0 + ee) * (NN * NN) + 4 * l;
        *reinterpret_cast<float4*>(out_x + base) = xo;
        *reinterpret_cast<float4*>(out_w + base) = wo;
    }
}

extern "C" void kernel_launch(void* const* d_in, const int* in_sizes, int n_in,
                              void* d_out, int out_size, void* d_ws, size_t ws_size,
                              hipStream_t stream) {
    const float* obs      = (const float*)d_in[0];
    const float* policies = (const float*)d_in[1];
    const float* actions  = (const float*)d_in[2];
    const float* W1       = (const float*)d_in[3];
    const float* b1       = (const float*)d_in[4];
    const float* W2       = (const float*)d_in[5];
    const float* b2       = (const float*)d_in[6];
    const float* Wfc      = (const float*)d_in[7];
    const float* Wattn    = (const float*)d_in[8];
    const float* Wv       = (const float*)d_in[9];
    const float* bv       = (const float*)d_in[10];

    float* out_x = (float*)d_out;                    // [B*N*N] = 1048576
    float* out_w = out_x + (size_t)BB * NN * NN;     // second tuple element

    critic_kernel<<<BB / GENV, NTHR, 0, stream>>>(obs, policies, actions,
                                                  W1, b1, W2, b2, Wfc, Wattn, Wv, bv,
                                                  out_x, out_w);
}

// Round 6
// 20.157 us; speedup vs baseline: 1.2023x; 1.0900x over previous
//
#include <hip/hip_runtime.h>

// Problem constants (fixed by the reference)
#define BB   4096
#define NN   16
#define AA   8
#define DIN  128
#define H1C  64
#define DPC  64
#define DZC  64

#define GENV 8     // envs per block == waves per block (wave w <-> env w)
#define NTHR 512   // 8 waves

// Collapsed reference (round-0 derivation; verified passing R1/R3/R4/R5):
//   agg   = mean_n obs[b,n,:]                      [128]
//   h     = relu(agg @ W1 + b1)                    [64]
//   (p eliminated:)  u = Wfc @ (Wattn[:64]+Wattn[64:]);  v1 = W2 @ u;  v2 = W2 @ Wv[:64]
//   logit = h.v1 + b2.u ;  wgt = sigmoid(leaky_relu(logit))   -> entire w output
//   c     = h.v2 + b2.Wv[:64] + bv
//   dv[j] = (pi[b,j]-act[b,j]) . Wv[64:72]         [16]
//   Sv    = sum(pi.v) - wgt * sum((pi-act).v)
//   x[b,d,j] = c + (Sv + wgt*dv[j]) / 16           (independent of d)
__global__ __launch_bounds__(NTHR, 4)
void critic_kernel(const float* __restrict__ obs,      // [B*N, 128]
                   const float* __restrict__ policies, // [B*N, 8]
                   const float* __restrict__ actions,  // [B*N, 8]
                   const float* __restrict__ W1,       // [128,64]
                   const float* __restrict__ b1,       // [64]
                   const float* __restrict__ W2,       // [64,64]
                   const float* __restrict__ b2,       // [64]
                   const float* __restrict__ Wfc,      // [64,64]
                   const float* __restrict__ Wattn,    // [128]
                   const float* __restrict__ Wv,       // [72]
                   const float* __restrict__ bv,       // [1]
                   float* __restrict__ out_x,          // [B*N*N]
                   float* __restrict__ out_w)          // [B*N*N]
{
    __shared__ float sW1[DIN * H1C];    // 32 KB
    __shared__ float sAgg[GENV][DIN];   // 4 KB
    __shared__ float sV1[H1C];          // 256 B
    __shared__ float sV2[H1C];          // 256 B
    __shared__ float sS[2];             // tb2u, tb2w
    __shared__ float sDv[GENV][16];     // 512 B    -> ~37 KB total

    const int tid = threadIdx.x;
    const int l   = tid & 63;
    const int w   = tid >> 6;                    // wave id == local env id
    const int e   = blockIdx.x * GENV + w;       // this wave's env

    // ---- phase-1 obs loads: thread = (env w, float2-column l). 16 independent
    //      coalesced loads (512 B per wave-instruction), no cross-lane deps. ----
    const float2* o2p = reinterpret_cast<const float2*>(obs) + (size_t)e * (NN * DIN / 2);
    float2 ov[NN];
    #pragma unroll
    for (int r = 0; r < NN; ++r) ov[r] = o2p[r * 64 + l];

    // ---- stage W1 into LDS (cooperative, 4 float4 per thread) ----
    {
        const float4* g1 = reinterpret_cast<const float4*>(W1);
        float4*       s1 = reinterpret_cast<float4*>(sW1);
        #pragma unroll
        for (int i = 0; i < (DIN * H1C / 4) / NTHR; ++i)
            s1[i * NTHR + tid] = g1[i * NTHR + tid];
    }

    // ---- this wave's pol/act loads (early issue) ----
    const float* Pb = policies + (size_t)e * (NN * AA);
    const float* Ab = actions  + (size_t)e * (NN * AA);
    const float pv0 = Pb[l], pv1 = Pb[64 + l];
    const float av0 = Ab[l], av1 = Ab[64 + l];

    // ---- small params (all waves) ----
    const float b1v = b1[l];
    const float va  = Wv[64 + (l & 7)];
    const float bvv = bv[0];

    // ---- wave 7: env-independent u/v1/v2 (register+shuffle form, R5-passing
    //      accumulation order j=0..63). Overlaps other waves' obs latency. ----
    if (w == 7) {
        const float b2v  = b2[l];
        const float wsum = Wattn[l] + Wattn[DZC + l];
        const float wvv  = Wv[l];

        float u = 0.0f;
        {
            const float4* WfcR = reinterpret_cast<const float4*>(Wfc) + (size_t)l * (DZC / 4);
            float4 wb[8];
            #pragma unroll
            for (int pass = 0; pass < 2; ++pass) {
                #pragma unroll
                for (int j = 0; j < 8; ++j) wb[j] = WfcR[pass * 8 + j];
                #pragma unroll
                for (int j = 0; j < 8; ++j) {
                    const int jj = pass * 32 + 4 * j;
                    u = fmaf(wb[j].x, __shfl(wsum, jj + 0), u);
                    u = fmaf(wb[j].y, __shfl(wsum, jj + 1), u);
                    u = fmaf(wb[j].z, __shfl(wsum, jj + 2), u);
                    u = fmaf(wb[j].w, __shfl(wsum, jj + 3), u);
                }
            }
        }
        float v1 = 0.0f, v2 = 0.0f;
        {
            const float4* W2R = reinterpret_cast<const float4*>(W2) + (size_t)l * (DPC / 4);
            float4 wb[8];
            #pragma unroll
            for (int pass = 0; pass < 2; ++pass) {
                #pragma unroll
                for (int j = 0; j < 8; ++j) wb[j] = W2R[pass * 8 + j];
                #pragma unroll
                for (int j = 0; j < 8; ++j) {
                    const int jj = pass * 32 + 4 * j;
                    v1 = fmaf(wb[j].x, __shfl(u, jj + 0), v1);
                    v1 = fmaf(wb[j].y, __shfl(u, jj + 1), v1);
                    v1 = fmaf(wb[j].z, __shfl(u, jj + 2), v1);
                    v1 = fmaf(wb[j].w, __shfl(u, jj + 3), v1);
                    v2 = fmaf(wb[j].x, __shfl(wvv, jj + 0), v2);
                    v2 = fmaf(wb[j].y, __shfl(wvv, jj + 1), v2);
                    v2 = fmaf(wb[j].z, __shfl(wvv, jj + 2), v2);
                    v2 = fmaf(wb[j].w, __shfl(wvv, jj + 3), v2);
                }
            }
        }
        float tb2u = b2v * u;
        float tb2w = b2v * wvv;
        #pragma unroll
        for (int m = 32; m >= 1; m >>= 1) {
            tb2u += __shfl_xor(tb2u, m);
            tb2w += __shfl_xor(tb2w, m);
        }
        sV1[l] = v1;
        sV2[l] = v2;
        if (l == 0) { sS[0] = tb2u; sS[1] = tb2w; }
    }

    // ---- phase-1 reduce: serial sum over the 16 rows (no shuffles) ----
    {
        float sx = 0.0f, sy = 0.0f;
        #pragma unroll
        for (int r = 0; r < NN; ++r) { sx += ov[r].x; sy += ov[r].y; }
        const float inv = 1.0f / 16.0f;
        *reinterpret_cast<float2*>(&sAgg[w][2 * l]) = make_float2(sx * inv, sy * inv);
    }

    __syncthreads();   // sW1, sAgg, sV1/sV2/sS all visible

    // ---- mv1: h = relu(agg @ W1 + b1); 4 independent 32-FMA chains ----
    float a0 = b1v, a1 = 0.0f, a2 = 0.0f, a3 = 0.0f;
    #pragma unroll
    for (int d4 = 0; d4 < DIN / 4; ++d4) {
        const float4 ag = *reinterpret_cast<const float4*>(&sAgg[w][4 * d4]);  // broadcast
        a0 = fmaf(ag.x, sW1[(4 * d4 + 0) * H1C + l], a0);
        a1 = fmaf(ag.y, sW1[(4 * d4 + 1) * H1C + l], a1);
        a2 = fmaf(ag.z, sW1[(4 * d4 + 2) * H1C + l], a2);
        a3 = fmaf(ag.w, sW1[(4 * d4 + 3) * H1C + l], a3);
    }
    const float h = fmaxf((a0 + a1) + (a2 + a3), 0.0f);

    // ---- per-env scalars (R3/R4 trees) ----
    const float v1l = sV1[l];
    const float v2l = sV2[l];
    const float tb2u = sS[0];
    const float tb2w = sS[1];

    float t0 = h * v1l;
    float t1 = h * v2l;
    #pragma unroll
    for (int m = 32; m >= 1; m >>= 1) {
        t0 += __shfl_xor(t0, m);
        t1 += __shfl_xor(t1, m);
    }
    const float logit = t0 + tb2u;
    const float eV  = (logit > 0.0f) ? logit : 0.01f * logit;   // leaky slope 0.01
    const float wgt = 1.0f / (1.0f + expf(-eV));
    const float c   = t1 + tb2w + bvv;

    float q0 = (pv0 - av0) * va;   // -> dv[l>>3]
    float q1 = (pv1 - av1) * va;   // -> dv[8+(l>>3)]
    float fq = q0 + q1;
    float fp = (pv0 + pv1) * va;
    #pragma unroll
    for (int m = 1; m <= 4; m <<= 1) {     // segmented 8-lane reduce (over a)
        q0 += __shfl_xor(q0, m);
        q1 += __shfl_xor(q1, m);
    }
    #pragma unroll
    for (int m = 32; m >= 1; m >>= 1) {    // full-wave reduces (R3 tree)
        fq += __shfl_xor(fq, m);
        fp += __shfl_xor(fp, m);
    }
    const float Sv = fp - wgt * fq;

    if ((l & 7) == 0) {
        sDv[w][l >> 3]       = q0;
        sDv[w][8 + (l >> 3)] = q1;
    }

    __syncthreads();   // sDv visible

    // ---- outputs: 16 distinct x per env, broadcast over d; w scalar ----
    const float invN = 1.0f / 16.0f;
    const int j0 = (4 * l) & 15;          // 0,4,8,12; j0..j0+3 never wrap
    float4 xo, wo;
    xo.x = fmaf(wgt, sDv[w][j0 + 0], Sv) * invN + c;
    xo.y = fmaf(wgt, sDv[w][j0 + 1], Sv) * invN + c;
    xo.z = fmaf(wgt, sDv[w][j0 + 2], Sv) * invN + c;
    xo.w = fmaf(wgt, sDv[w][j0 + 3], Sv) * invN + c;
    wo.x = wo.y = wo.z = wo.w = wgt;

    const size_t base = (size_t)e * (NN * NN) + 4 * l;
    *reinterpret_cast<float4*>(out_x + base) = xo;
    *reinterpret_cast<float4*>(out_w + base) = wo;
}

extern "C" void kernel_launch(void* const* d_in, const int* in_sizes, int n_in,
                              void* d_out, int out_size, void* d_ws, size_t ws_size,
                              hipStream_t stream) {
    const float* obs      = (const float*)d_in[0];
    const float* policies = (const float*)d_in[1];
    const float* actions  = (const float*)d_in[2];
    const float* W1       = (const float*)d_in[3];
    const float* b1       = (const float*)d_in[4];
    const float* W2       = (const float*)d_in[5];
    const float* b2       = (const float*)d_in[6];
    const float* Wfc      = (const float*)d_in[7];
    const float* Wattn    = (const float*)d_in[8];
    const float* Wv       = (const float*)d_in[9];
    const float* bv       = (const float*)d_in[10];

    float* out_x = (float*)d_out;                    // [B*N*N] = 1048576
    float* out_w = out_x + (size_t)BB * NN * NN;     // second tuple element

    critic_kernel<<<BB / GENV, NTHR, 0, stream>>>(obs, policies, actions,
                                                  W1, b1, W2, b2, Wfc, Wattn, Wv, bv,
                                                  out_x, out_w);
}

// Round 7
// 17.801 us; speedup vs baseline: 1.3614x; 1.1323x over previous
//
#include <hip/hip_runtime.h>

// Problem constants (fixed by the reference)
#define BB   4096
#define NN   16
#define AA   8
#define DIN  128
#define H1C  64
#define DPC  64
#define DZC  64

#define GENV 8     // envs per block == waves per block (wave w <-> env w)
#define NTHR 512   // 8 waves
#define LDT  132   // padded row length of transposed-W1 LDS tile (33 float4)

// Collapsed reference (round-0 derivation; verified passing R1/R3/R4/R5/R6):
//   agg   = mean_n obs[b,n,:]                      [128]
//   h     = relu(agg @ W1 + b1)                    [64]
//   (p eliminated:)  u = Wfc @ (Wattn[:64]+Wattn[64:]);  v1 = W2 @ u;  v2 = W2 @ Wv[:64]
//   logit = h.v1 + b2.u ;  wgt = sigmoid(leaky_relu(logit))   -> entire w output
//   c     = h.v2 + b2.Wv[:64] + bv
//   dv[j] = (pi[b,j]-act[b,j]) . Wv[64:72]         [16]
//   Sv    = sum(pi.v) - wgt * sum((pi-act).v)
//   x[b,d,j] = c + (Sv + wgt*dv[j]) / 16           (independent of d)
__global__ __launch_bounds__(NTHR, 4)
void critic_kernel(const float* __restrict__ obs,      // [B*N, 128]
                   const float* __restrict__ policies, // [B*N, 8]
                   const float* __restrict__ actions,  // [B*N, 8]
                   const float* __restrict__ W1,       // [128,64]
                   const float* __restrict__ b1,       // [64]
                   const float* __restrict__ W2,       // [64,64]
                   const float* __restrict__ b2,       // [64]
                   const float* __restrict__ Wfc,      // [64,64]
                   const float* __restrict__ Wattn,    // [128]
                   const float* __restrict__ Wv,       // [72]
                   const float* __restrict__ bv,       // [1]
                   float* __restrict__ out_x,          // [B*N*N]
                   float* __restrict__ out_w)          // [B*N*N]
{
    __shared__ float sW1T[H1C][LDT];    // 33 KB: sW1T[c][d] = W1[d][c] (transposed)
    __shared__ float sAgg[GENV][DIN];   // 4 KB
    __shared__ float sV1[H1C];          // 256 B
    __shared__ float sV2[H1C];          // 256 B
    __shared__ float sS[2];             // tb2u, tb2w
    __shared__ float sDv[GENV][16];     // 512 B
    __shared__ float sWsum[DZC];        // wave-7 private scratch
    __shared__ float sWv64[DPC];
    __shared__ float sU[DPC];           //   -> ~39 KB total, 2 blocks/CU

    const int tid = threadIdx.x;
    const int l   = tid & 63;
    const int w   = tid >> 6;                    // wave id == local env id
    const int e   = blockIdx.x * GENV + w;       // this wave's env

    // ---- phase-1 obs loads: thread = (env w, float2-column l). 16 independent
    //      coalesced loads, no cross-lane deps. ----
    const float2* o2p = reinterpret_cast<const float2*>(obs) + (size_t)e * (NN * DIN / 2);
    float2 ov[NN];
    #pragma unroll
    for (int r = 0; r < NN; ++r) ov[r] = o2p[r * 64 + l];

    // ---- stage W1 TRANSPOSED into LDS (4 float4 global reads -> 16 scalar writes) ----
    {
        const float4* g1 = reinterpret_cast<const float4*>(W1);
        #pragma unroll
        for (int i = 0; i < (DIN * H1C / 4) / NTHR; ++i) {
            const int g = i * NTHR + tid;        // float4 index 0..2047
            const float4 v = g1[g];
            const int d  = g >> 4;               // W1 row 0..127
            const int c4 = (g & 15) * 4;         // W1 col base 0..60
            sW1T[c4 + 0][d] = v.x;
            sW1T[c4 + 1][d] = v.y;
            sW1T[c4 + 2][d] = v.z;
            sW1T[c4 + 3][d] = v.w;
        }
    }

    // ---- this wave's pol/act loads (early issue) ----
    const float* Pb = policies + (size_t)e * (NN * AA);
    const float* Ab = actions  + (size_t)e * (NN * AA);
    const float pv0 = Pb[l], pv1 = Pb[64 + l];
    const float av0 = Ab[l], av1 = Ab[64 + l];

    // ---- small params (all waves) ----
    const float b1v = b1[l];
    const float va  = Wv[64 + (l & 7)];
    const float bvv = bv[0];

    // ---- wave 7: env-independent u/v1/v2 via same-wave LDS broadcasts
    //      (R4-passing accumulation order; no barriers needed within a wave). ----
    if (w == 7) {
        const float b2v  = b2[l];
        const float wsum = Wattn[l] + Wattn[DZC + l];
        const float wvv  = Wv[l];
        sWsum[l] = wsum;
        sWv64[l] = wvv;

        float u = 0.0f;
        {
            const float4* WfcR = reinterpret_cast<const float4*>(Wfc) + (size_t)l * (DZC / 4);
            const float4* ws4  = reinterpret_cast<const float4*>(sWsum);
            #pragma unroll
            for (int j4 = 0; j4 < DZC / 4; ++j4) {
                const float4 wq = WfcR[j4];
                const float4 s  = ws4[j4];          // LDS broadcast (same-wave RAW)
                u = fmaf(wq.x, s.x, u); u = fmaf(wq.y, s.y, u);
                u = fmaf(wq.z, s.z, u); u = fmaf(wq.w, s.w, u);
            }
        }
        sU[l] = u;
        float v1 = 0.0f, v2 = 0.0f;
        {
            const float4* W2R = reinterpret_cast<const float4*>(W2) + (size_t)l * (DPC / 4);
            const float4* su4 = reinterpret_cast<const float4*>(sU);
            const float4* sv4 = reinterpret_cast<const float4*>(sWv64);
            #pragma unroll
            for (int j4 = 0; j4 < DPC / 4; ++j4) {
                const float4 wq = W2R[j4];
                const float4 a  = su4[j4];
                const float4 b  = sv4[j4];
                v1 = fmaf(wq.x, a.x, v1); v1 = fmaf(wq.y, a.y, v1);
                v1 = fmaf(wq.z, a.z, v1); v1 = fmaf(wq.w, a.w, v1);
                v2 = fmaf(wq.x, b.x, v2); v2 = fmaf(wq.y, b.y, v2);
                v2 = fmaf(wq.z, b.z, v2); v2 = fmaf(wq.w, b.w, v2);
            }
        }
        float tb2u = b2v * u;
        float tb2w = b2v * wvv;
        #pragma unroll
        for (int m = 32; m >= 1; m >>= 1) {
            tb2u += __shfl_xor(tb2u, m);
            tb2w += __shfl_xor(tb2w, m);
        }
        sV1[l] = v1;
        sV2[l] = v2;
        if (l == 0) { sS[0] = tb2u; sS[1] = tb2w; }
    }

    // ---- phase-1 reduce: serial sum over the 16 rows (R6 order) ----
    {
        float sx = 0.0f, sy = 0.0f;
        #pragma unroll
        for (int r = 0; r < NN; ++r) { sx += ov[r].x; sy += ov[r].y; }
        const float inv = 1.0f / 16.0f;
        *reinterpret_cast<float2*>(&sAgg[w][2 * l]) = make_float2(sx * inv, sy * inv);
    }

    __syncthreads();   // sW1T (cross-wave), sAgg, sV1/sV2/sS all visible

    // ---- mv1: h = relu(agg @ W1 + b1); 4 independent 32-FMA chains.
    //      Same values & order as R6; weights now one ds_read_b128 per 4. ----
    float a0 = b1v, a1 = 0.0f, a2 = 0.0f, a3 = 0.0f;
    #pragma unroll
    for (int d4 = 0; d4 < DIN / 4; ++d4) {
        const float4 w4 = *reinterpret_cast<const float4*>(&sW1T[l][4 * d4]);
        const float4 ag = *reinterpret_cast<const float4*>(&sAgg[w][4 * d4]);  // broadcast
        a0 = fmaf(ag.x, w4.x, a0);
        a1 = fmaf(ag.y, w4.y, a1);
        a2 = fmaf(ag.z, w4.z, a2);
        a3 = fmaf(ag.w, w4.w, a3);
    }
    const float h = fmaxf((a0 + a1) + (a2 + a3), 0.0f);

    // ---- per-env scalars (R3/R4/R6 trees) ----
    const float v1l  = sV1[l];
    const float v2l  = sV2[l];
    const float tb2u = sS[0];
    const float tb2w = sS[1];

    float t0 = h * v1l;
    float t1 = h * v2l;
    #pragma unroll
    for (int m = 32; m >= 1; m >>= 1) {
        t0 += __shfl_xor(t0, m);
        t1 += __shfl_xor(t1, m);
    }
    const float logit = t0 + tb2u;
    const float eV  = (logit > 0.0f) ? logit : 0.01f * logit;   // leaky slope 0.01
    const float wgt = 1.0f / (1.0f + expf(-eV));
    const float c   = t1 + tb2w + bvv;

    float q0 = (pv0 - av0) * va;   // -> dv[l>>3]
    float q1 = (pv1 - av1) * va;   // -> dv[8+(l>>3)]
    float fq = q0 + q1;
    float fp = (pv0 + pv1) * va;
    #pragma unroll
    for (int m = 1; m <= 4; m <<= 1) {     // segmented 8-lane reduce (over a)
        q0 += __shfl_xor(q0, m);
        q1 += __shfl_xor(q1, m);
    }
    #pragma unroll
    for (int m = 32; m >= 1; m >>= 1) {    // full-wave reduces (R3 tree)
        fq += __shfl_xor(fq, m);
        fp += __shfl_xor(fp, m);
    }
    const float Sv = fp - wgt * fq;

    if ((l & 7) == 0) {
        sDv[w][l >> 3]       = q0;
        sDv[w][8 + (l >> 3)] = q1;
    }
    // sDv[w] is written and read by the SAME wave -> program-order LDS
    // (compiler lgkmcnt) suffices; no cross-wave dependency here.

    // ---- outputs: 16 distinct x per env, broadcast over d; w scalar ----
    const float invN = 1.0f / 16.0f;
    const int j0 = (4 * l) & 15;          // 0,4,8,12; j0..j0+3 never wrap
    float4 xo, wo;
    xo.x = fmaf(wgt, sDv[w][j0 + 0], Sv) * invN + c;
    xo.y = fmaf(wgt, sDv[w][j0 + 1], Sv) * invN + c;
    xo.z = fmaf(wgt, sDv[w][j0 + 2], Sv) * invN + c;
    xo.w = fmaf(wgt, sDv[w][j0 + 3], Sv) * invN + c;
    wo.x = wo.y = wo.z = wo.w = wgt;

    const size_t base = (size_t)e * (NN * NN) + 4 * l;
    *reinterpret_cast<float4*>(out_x + base) = xo;
    *reinterpret_cast<float4*>(out_w + base) = wo;
}

extern "C" void kernel_launch(void* const* d_in, const int* in_sizes, int n_in,
                              void* d_out, int out_size, void* d_ws, size_t ws_size,
                              hipStream_t stream) {
    const float* obs      = (const float*)d_in[0];
    const float* policies = (const float*)d_in[1];
    const float* actions  = (const float*)d_in[2];
    const float* W1       = (const float*)d_in[3];
    const float* b1       = (const float*)d_in[4];
    const float* W2       = (const float*)d_in[5];
    const float* b2       = (const float*)d_in[6];
    const float* Wfc      = (const float*)d_in[7];
    const float* Wattn    = (const float*)d_in[8];
    const float* Wv       = (const float*)d_in[9];
    const float* bv       = (const float*)d_in[10];

    float* out_x = (float*)d_out;                    // [B*N*N] = 1048576
    float* out_w = out_x + (size_t)BB * NN * NN;     // second tuple element

    critic_kernel<<<BB / GENV, NTHR, 0, stream>>>(obs, policies, actions,
                                                  W1, b1, W2, b2, Wfc, Wattn, Wv, bv,
                                                  out_x, out_w);
}

// Round 8
// 17.424 us; speedup vs baseline: 1.3908x; 1.0216x over previous
//
#include <hip/hip_runtime.h>

// Problem constants (fixed by the reference)
#define BB   4096
#define NN   16
#define AA   8
#define DIN  128
#define H1C  64
#define DPC  64
#define DZC  64

#define GENV 8     // envs per block == waves per block (wave w <-> env w)
#define NTHR 512   // 8 waves

// Collapsed reference (round-0 derivation; verified passing R1/R3/R4/R5/R6/R7):
//   agg   = mean_n obs[b,n,:]                      [128]
//   h     = relu(agg @ W1 + b1)                    [64]
//   (p eliminated:)  u = Wfc @ (Wattn[:64]+Wattn[64:]);  v1 = W2 @ u;  v2 = W2 @ Wv[:64]
//   logit = h.v1 + b2.u ;  wgt = sigmoid(leaky_relu(logit))   -> entire w output
//   c     = h.v2 + b2.Wv[:64] + bv
//   dv[j] = (pi[b,j]-act[b,j]) . Wv[64:72]         [16]
//   Sv    = sum(pi.v) - wgt * sum((pi-act).v)
//   x[b,d,j] = c + (Sv + wgt*dv[j]) / 16           (independent of d)

__device__ __forceinline__ float lane_bcast(float v, int lane) {
    return __int_as_float(__builtin_amdgcn_readlane(__float_as_int(v), lane));
}

__global__ __launch_bounds__(NTHR, 4)
void critic_kernel(const float* __restrict__ obs,      // [B*N, 128]
                   const float* __restrict__ policies, // [B*N, 8]
                   const float* __restrict__ actions,  // [B*N, 8]
                   const float* __restrict__ W1,       // [128,64]
                   const float* __restrict__ b1,       // [64]
                   const float* __restrict__ W2,       // [64,64]
                   const float* __restrict__ b2,       // [64]
                   const float* __restrict__ Wfc,      // [64,64]
                   const float* __restrict__ Wattn,    // [128]
                   const float* __restrict__ Wv,       // [72]
                   const float* __restrict__ bv,       // [1]
                   float* __restrict__ out_x,          // [B*N*N]
                   float* __restrict__ out_w)          // [B*N*N]
{
    // W1 transposed tile, XOR-swizzled at float4 granularity:
    //   element block [c][4*d4..4*d4+3] lives at sW1T4[c*32 + (d4 ^ (c&7))].
    // Row stride = 32 float4 = 512 B; the XOR spreads the 8 rows of each
    // 8-lane group across all 32 banks -> conflict-free ds_read_b128 (T2/G4).
    __shared__ float4 sW1T4[H1C * 32];  // 32 KB
    __shared__ float sV1[H1C];          // 256 B
    __shared__ float sV2[H1C];          // 256 B
    __shared__ float sS[2];             // tb2u, tb2w
    __shared__ float sDv[GENV][16];     // 512 B
    __shared__ float sWsum[DZC];        // wave-7 private scratch
    __shared__ float sWv64[DPC];
    __shared__ float sU[DPC];           //   -> ~34.6 KB total

    const int tid = threadIdx.x;
    const int l   = tid & 63;
    const int w   = tid >> 6;                    // wave id == local env id
    const int e   = blockIdx.x * GENV + w;       // this wave's env

    // ---- stage W1 transposed+swizzled: thread = (col c, row-group grp).
    //      4 coalesced scalar loads -> one conflict-free ds_write_b128. ----
    {
        const int c   = tid & 63;
        const int grp = tid >> 6;
        #pragma unroll
        for (int i = 0; i < 4; ++i) {
            const int d0 = 4 * (i * 8 + grp);     // 0,4,...,124
            const float w0  = W1[(d0 + 0) * H1C + c];
            const float w1_ = W1[(d0 + 1) * H1C + c];
            const float w2_ = W1[(d0 + 2) * H1C + c];
            const float w3_ = W1[(d0 + 3) * H1C + c];
            sW1T4[c * 32 + ((d0 >> 2) ^ (c & 7))] = make_float4(w0, w1_, w2_, w3_);
        }
    }

    // ---- phase-1 obs loads: thread = (env w, float2-column l). ----
    const float2* o2p = reinterpret_cast<const float2*>(obs) + (size_t)e * (NN * DIN / 2);
    float2 ov[NN];
    #pragma unroll
    for (int r = 0; r < NN; ++r) ov[r] = o2p[r * 64 + l];

    // ---- this wave's pol/act loads (early issue) ----
    const float* Pb = policies + (size_t)e * (NN * AA);
    const float* Ab = actions  + (size_t)e * (NN * AA);
    const float pv0 = Pb[l], pv1 = Pb[64 + l];
    const float av0 = Ab[l], av1 = Ab[64 + l];

    // ---- small params (all waves) ----
    const float b1v = b1[l];
    const float va  = Wv[64 + (l & 7)];
    const float bvv = bv[0];

    // ---- wave 7: env-independent u/v1/v2 via same-wave LDS broadcasts
    //      (R7-passing form and order). Overlaps other waves' loads. ----
    if (w == 7) {
        const float b2v  = b2[l];
        const float wsum = Wattn[l] + Wattn[DZC + l];
        const float wvv  = Wv[l];
        sWsum[l] = wsum;
        sWv64[l] = wvv;

        float u = 0.0f;
        {
            const float4* WfcR = reinterpret_cast<const float4*>(Wfc) + (size_t)l * (DZC / 4);
            const float4* ws4  = reinterpret_cast<const float4*>(sWsum);
            #pragma unroll
            for (int j4 = 0; j4 < DZC / 4; ++j4) {
                const float4 wq = WfcR[j4];
                const float4 s  = ws4[j4];          // LDS broadcast (same-wave RAW)
                u = fmaf(wq.x, s.x, u); u = fmaf(wq.y, s.y, u);
                u = fmaf(wq.z, s.z, u); u = fmaf(wq.w, s.w, u);
            }
        }
        sU[l] = u;
        float v1 = 0.0f, v2 = 0.0f;
        {
            const float4* W2R = reinterpret_cast<const float4*>(W2) + (size_t)l * (DPC / 4);
            const float4* su4 = reinterpret_cast<const float4*>(sU);
            const float4* sv4 = reinterpret_cast<const float4*>(sWv64);
            #pragma unroll
            for (int j4 = 0; j4 < DPC / 4; ++j4) {
                const float4 wq = W2R[j4];
                const float4 a  = su4[j4];
                const float4 b  = sv4[j4];
                v1 = fmaf(wq.x, a.x, v1); v1 = fmaf(wq.y, a.y, v1);
                v1 = fmaf(wq.z, a.z, v1); v1 = fmaf(wq.w, a.w, v1);
                v2 = fmaf(wq.x, b.x, v2); v2 = fmaf(wq.y, b.y, v2);
                v2 = fmaf(wq.z, b.z, v2); v2 = fmaf(wq.w, b.w, v2);
            }
        }
        float tb2u = b2v * u;
        float tb2w = b2v * wvv;
        #pragma unroll
        for (int m = 32; m >= 1; m >>= 1) {
            tb2u += __shfl_xor(tb2u, m);
            tb2w += __shfl_xor(tb2w, m);
        }
        sV1[l] = v1;
        sV2[l] = v2;
        if (l == 0) { sS[0] = tb2u; sS[1] = tb2w; }
    }

    // ---- phase-1 reduce: serial sum over 16 rows; agg STAYS IN REGISTERS:
    //      lane l holds agg[2l] (ax), agg[2l+1] (ay).  (Same values/order as
    //      R6/R7, which round-tripped them through sAgg.) ----
    float ax, ay;
    {
        float sx = 0.0f, sy = 0.0f;
        #pragma unroll
        for (int r = 0; r < NN; ++r) { sx += ov[r].x; sy += ov[r].y; }
        const float inv = 1.0f / 16.0f;
        ax = sx * inv;
        ay = sy * inv;
    }

    // ---- pol/act trees (R3/R6/R7 order), hoisted pre-barrier to overlap ----
    float q0 = (pv0 - av0) * va;   // -> dv[l>>3]
    float q1 = (pv1 - av1) * va;   // -> dv[8+(l>>3)]
    float fq = q0 + q1;
    float fp = (pv0 + pv1) * va;
    #pragma unroll
    for (int m = 1; m <= 4; m <<= 1) {     // segmented 8-lane reduce (over a)
        q0 += __shfl_xor(q0, m);
        q1 += __shfl_xor(q1, m);
    }
    #pragma unroll
    for (int m = 32; m >= 1; m >>= 1) {    // full-wave reduces
        fq += __shfl_xor(fq, m);
        fp += __shfl_xor(fp, m);
    }
    if ((l & 7) == 0) {
        sDv[w][l >> 3]       = q0;         // same-wave write; barrier also covers it
        sDv[w][8 + (l >> 3)] = q1;
    }

    __syncthreads();   // sW1T4 (cross-wave), sV1/sV2/sS visible

    // ---- mv1: h = relu(agg @ W1 + b1); 4 independent chains, weights via
    //      conflict-free swizzled b128, agg via v_readlane (VALU pipe). ----
    float a0 = b1v, a1 = 0.0f, a2 = 0.0f, a3 = 0.0f;
    #pragma unroll
    for (int d4 = 0; d4 < DIN / 4; ++d4) {
        const float4 w4 = sW1T4[l * 32 + (d4 ^ (l & 7))];
        a0 = fmaf(lane_bcast(ax, 2 * d4),     w4.x, a0);   // agg[4d4]
        a1 = fmaf(lane_bcast(ay, 2 * d4),     w4.y, a1);   // agg[4d4+1]
        a2 = fmaf(lane_bcast(ax, 2 * d4 + 1), w4.z, a2);   // agg[4d4+2]
        a3 = fmaf(lane_bcast(ay, 2 * d4 + 1), w4.w, a3);   // agg[4d4+3]
    }
    const float h = fmaxf((a0 + a1) + (a2 + a3), 0.0f);

    // ---- per-env scalars (R7 trees) ----
    const float v1l  = sV1[l];
    const float v2l  = sV2[l];
    const float tb2u = sS[0];
    const float tb2w = sS[1];

    float t0 = h * v1l;
    float t1 = h * v2l;
    #pragma unroll
    for (int m = 32; m >= 1; m >>= 1) {
        t0 += __shfl_xor(t0, m);
        t1 += __shfl_xor(t1, m);
    }
    const float logit = t0 + tb2u;
    const float eV  = (logit > 0.0f) ? logit : 0.01f * logit;   // leaky slope 0.01
    const float wgt = 1.0f / (1.0f + expf(-eV));
    const float c   = t1 + tb2w + bvv;
    const float Sv  = fp - wgt * fq;

    // ---- outputs: 16 distinct x per env, broadcast over d; w scalar ----
    const float invN = 1.0f / 16.0f;
    const int j0 = (4 * l) & 15;          // 0,4,8,12; j0..j0+3 never wrap
    float4 xo, wo;
    xo.x = fmaf(wgt, sDv[w][j0 + 0], Sv) * invN + c;
    xo.y = fmaf(wgt, sDv[w][j0 + 1], Sv) * invN + c;
    xo.z = fmaf(wgt, sDv[w][j0 + 2], Sv) * invN + c;
    xo.w = fmaf(wgt, sDv[w][j0 + 3], Sv) * invN + c;
    wo.x = wo.y = wo.z = wo.w = wgt;

    const size_t base = (size_t)e * (NN * NN) + 4 * l;
    *reinterpret_cast<float4*>(out_x + base) = xo;
    *reinterpret_cast<float4*>(out_w + base) = wo;
}

extern "C" void kernel_launch(void* const* d_in, const int* in_sizes, int n_in,
                              void* d_out, int out_size, void* d_ws, size_t ws_size,
                              hipStream_t stream) {
    const float* obs      = (const float*)d_in[0];
    const float* policies = (const float*)d_in[1];
    const float* actions  = (const float*)d_in[2];
    const float* W1       = (const float*)d_in[3];
    const float* b1       = (const float*)d_in[4];
    const float* W2       = (const float*)d_in[5];
    const float* b2       = (const float*)d_in[6];
    const float* Wfc      = (const float*)d_in[7];
    const float* Wattn    = (const float*)d_in[8];
    const float* Wv       = (const float*)d_in[9];
    const float* bv       = (const float*)d_in[10];

    float* out_x = (float*)d_out;                    // [B*N*N] = 1048576
    float* out_w = out_x + (size_t)BB * NN * NN;     // second tuple element

    critic_kernel<<<BB / GENV, NTHR, 0, stream>>>(obs, policies, actions,
                                                  W1, b1, W2, b2, Wfc, Wattn, Wv, bv,
                                                  out_x, out_w);
}